// Round 7
// baseline (361.042 us; speedup 1.0000x reference)
//
#include <hip/hip_runtime.h>
#include <hip/hip_bf16.h>
#include <hip/hip_fp8.h>
#include <cstdint>
#include <cstddef>

// ---------------- problem constants ----------------
#define M_TOK 4096          // B*S = 4*1024 tokens
#define HID   1024
#define NHEAD 16002
#define NHEAD_PAD 16384     // 64*256 (padded to 256-tile multiple)
#define P0    256
#define N0    12000
#define N0_PAD 12288        // 48*256
#define P1    64
#define N1    8000
#define N1_PAD 8192         // 32*256
#define PFUSE 384           // fused proj width: 256 + 128(pad of 64)
#define PREAL 320           // real cols in fused proj: 256 + 64

typedef unsigned char u8;
typedef float f32x4 __attribute__((ext_vector_type(4)));
typedef int   i32x4 __attribute__((ext_vector_type(4)));
typedef int   i32x8 __attribute__((ext_vector_type(8)));

// async global->LDS, 16B per lane; lds ptr = wave-uniform base, HW scatters lane*16.
__device__ __forceinline__ void load16(const void* g, void* l) {
    __builtin_amdgcn_global_load_lds(
        (__attribute__((address_space(1))) void*)g,
        (__attribute__((address_space(3))) void*)l,
        16, 0, 0);
}

__device__ __forceinline__ u8 to_e4m3(float f) {
    __hip_fp8_e4m3 h(f);
    return (u8)h.__x;
}

union Frag { struct { i32x4 lo, hi; } half; i32x8 v; };

// =====================================================================
// Round-7 lse3: 256x256 tile, BK=128, 16 waves (4x4) of 64x64 each,
// mfma_scale_f32_16x16x128_f8f6f4. 1024 threads, 1 block/CU, 128 KB LDS
// double-buffered.
//
// NEW vs round-6 (T3+T4+T5 fine-phase port of the m201 template):
// each k-tile is split into 4 barrier-bracketed PHASES (phase p = MFMA
// row mt=p). Per phase: {ds_reads issued BEFORE the barrier (latency
// overlaps other waves' MFMAs) -> s_barrier -> lgkmcnt(0)+sched_barrier
// (rule-18 fence) -> setprio(1) -> 4 MFMA -> setprio(0) -> s_barrier}.
// Next-tile staging spread across phases 0-1 (2 global_load_lds each);
// single vmcnt(0) at end of phase 3 (youngest prefetch ~2 phases old ->
// free), never a mid-compute drain. Round-6 evidence: round time 9060cyc
// vs max pipe demand ~3600 -> phase-serialization; m196/m218b measured
// +28-41% (interleave) and +21-25% (setprio) for exactly this change on
// 256^2 gfx950.
//
// Race audit: MFMAs read only own-wave pre-barrier ds_reads (lgkmcnt(0));
// buf^1 gloads are issued only after the barrier at which all reads of
// buf^1 retired; end-of-tile vmcnt(0)+barrier publishes all waves'
// staged data before any phase-0 read of the new buffer.
// =====================================================================
struct Seg {
    const u8* A; int lda;
    const u8* BT; int ldb;
    const float* bias; int K; int realN;
    const int* tgt; float* sumexp; float* lab;
    int nblk;   // 16 m-tiles x NT n-tiles, NT even; nblk % 32 == 0
};

__launch_bounds__(1024, 4)
__global__ void gemm_lse3(Seg s0, Seg s1, Seg s2) {
    __shared__ __align__(16) u8 As[2 * 32768];
    __shared__ __align__(16) u8 Bs[2 * 32768];

    int b = blockIdx.x;
    Seg sg; int rel;
    if (b < s0.nblk)                { sg = s0; rel = b; }
    else if (b < s0.nblk + s1.nblk) { sg = s1; rel = b - s0.nblk; }
    else                            { sg = s2; rel = b - s0.nblk - s1.nblk; }
    // L2-locality swizzle: 32-block groups = 16 m-tiles x 2 n-tiles.
    int pair = rel >> 5, inner = rel & 31;
    int m0 = (inner >> 1) * 256;
    int n0 = (pair * 2 + (inner & 1)) * 256;

    const int lda = sg.lda, ldb = sg.ldb;
    const int tid  = threadIdx.x;
    const int lane = tid & 63;
    const int wave = tid >> 6;          // 0..15
    const int wm = wave >> 2, wn = wave & 3;
    const int q = lane >> 4, lrow = lane & 15;
    const int sw = lrow & 7;

    // staging: per matrix 2048 granules (256 rows x 8); 2 loads/thread/matrix.
    int aofs[2], bofs[2], lbase[2];
    #pragma unroll
    for (int p = 0; p < 2; p++) {
        int pg = wave * 128 + p * 64 + lane;          // 0..2047
        int row = pg >> 3, gcol = (pg & 7) ^ (row & 7);
        aofs[p]  = row * lda + gcol * 16;
        bofs[p]  = row * ldb + gcol * 16;
        lbase[p] = (wave * 128 + p * 64) * 16;        // wave-uniform LDS byte ofs
    }

    f32x4 acc[4][4];
    #pragma unroll
    for (int mt = 0; mt < 4; mt++)
        #pragma unroll
        for (int nt = 0; nt < 4; nt++)
            acc[mt][nt] = (f32x4)(0.0f);

    const u8* Ab = sg.A  + (size_t)m0 * lda;
    const u8* Bb = sg.BT + (size_t)n0 * ldb;

    // fragment LDS byte offsets (buf 0, mt/nt 0); +t*2048 per 16-row subtile.
    const int aLo = ((wm * 64 + lrow) * 8 + ((2 * q)     ^ sw)) * 16;
    const int aHi = ((wm * 64 + lrow) * 8 + ((2 * q + 1) ^ sw)) * 16;
    const int bLo = ((wn * 64 + lrow) * 8 + ((2 * q)     ^ sw)) * 16;
    const int bHi = ((wn * 64 + lrow) * 8 + ((2 * q + 1) ^ sw)) * 16;

    // -------- prologue: stage tile 0 into buf 0, drain, publish --------
    const int ntile = sg.K >> 7;
    #pragma unroll
    for (int p = 0; p < 2; p++) {
        load16(Ab + aofs[p], As + lbase[p]);
        load16(Bb + bofs[p], Bs + lbase[p]);
    }
    asm volatile("s_waitcnt vmcnt(0)" ::: "memory");
    __builtin_amdgcn_s_barrier();

    // -------- 4-phase K-loop --------
    int cur = 0;
    for (int t = 0; t < ntile; ++t, cur ^= 1) {
        const u8* Ac = As + cur * 32768;
        const u8* Bc = Bs + cur * 32768;
        u8* An = As + (cur ^ 1) * 32768;
        u8* Bn = Bs + (cur ^ 1) * 32768;
        const bool pf = (t + 1 < ntile);
        const int kn = (t + 1) << 7;

        Frag fb[4], fa;
        #pragma unroll
        for (int p = 0; p < 4; ++p) {
            // pre-barrier ds_reads for this phase (fb once, in phase 0)
            if (p == 0) {
                #pragma unroll
                for (int i = 0; i < 4; i++) {
                    fb[i].half.lo = *reinterpret_cast<const i32x4*>(Bc + bLo + i * 2048);
                    fb[i].half.hi = *reinterpret_cast<const i32x4*>(Bc + bHi + i * 2048);
                }
            }
            fa.half.lo = *reinterpret_cast<const i32x4*>(Ac + aLo + p * 2048);
            fa.half.hi = *reinterpret_cast<const i32x4*>(Ac + aHi + p * 2048);
            // spread next-tile staging: A in phase 0, B in phase 1
            if (pf && p == 0) {
                load16(Ab + kn + aofs[0], An + lbase[0]);
                load16(Ab + kn + aofs[1], An + lbase[1]);
            }
            if (pf && p == 1) {
                load16(Bb + kn + bofs[0], Bn + lbase[0]);
                load16(Bb + kn + bofs[1], Bn + lbase[1]);
            }
            __builtin_amdgcn_s_barrier();
            asm volatile("s_waitcnt lgkmcnt(0)" ::: "memory");
            __builtin_amdgcn_sched_barrier(0);
            __builtin_amdgcn_s_setprio(1);
            #pragma unroll
            for (int nt = 0; nt < 4; nt++)
                acc[p][nt] = __builtin_amdgcn_mfma_scale_f32_16x16x128_f8f6f4(
                    fa.v, fb[nt].v, acc[p][nt],
                    0, 0,                      // cbsz/blgp = fp8 e4m3
                    0, 0x7F7F7F7F,             // A scale: 2^0
                    0, 0x7A7A7A7A);            // B scale: 2^-5
            __builtin_amdgcn_s_setprio(0);
            if (p == 3)
                asm volatile("s_waitcnt vmcnt(0)" ::: "memory");  // staged data landed (cheap: loads ~2 phases old)
            __builtin_amdgcn_s_barrier();
        }
    }

    // ---- epilogue: C/D (16x16): col = lane&15, row = (lane>>4)*4 + reg
    int colg[4]; float bias_v[4];
    #pragma unroll
    for (int nt = 0; nt < 4; nt++) {
        colg[nt] = n0 + wn * 64 + nt * 16 + lrow;
        bias_v[nt] = (colg[nt] < sg.realN) ? sg.bias[colg[nt]] : 0.0f;
    }

    float* sred = reinterpret_cast<float*>(As);   // [4][256], reuse A LDS

    #pragma unroll
    for (int mt = 0; mt < 4; mt++) {
        int rloc = wm * 64 + mt * 16 + q * 4;     // token row within tile
        #pragma unroll
        for (int r = 0; r < 4; r++) {
            int tok = m0 + rloc + r;
            int tg = sg.tgt[tok];
            float ps = 0.0f;
            #pragma unroll
            for (int nt = 0; nt < 4; nt++) {
                if (colg[nt] < sg.realN) {
                    float logit = acc[mt][nt][r] + bias_v[nt];
                    ps += __expf(logit);
                    if (colg[nt] == tg) atomicAdd(&sg.lab[tok], logit);
                }
            }
            ps += __shfl_xor(ps, 1);
            ps += __shfl_xor(ps, 2);
            ps += __shfl_xor(ps, 4);
            ps += __shfl_xor(ps, 8);
            // slice write: (wn, row) written by exactly one lane
            if (lrow == 0) sred[wn * 256 + rloc + r] = ps;
        }
    }
    __syncthreads();
    if (tid < 256) {
        float v = sred[tid] + sred[256 + tid] + sred[512 + tid] + sred[768 + tid];
        atomicAdd(&sg.sumexp[m0 + tid], v);
    }
}

// =====================================================================
// proj GEMM: unchanged round-5 structure (128x128, 8 waves of 64x32,
// single-buffer 32KB LDS, __syncthreads rounds). Small kernel; proven.
// =====================================================================
__launch_bounds__(512, 6)
__global__ void gemm_proj(const u8* __restrict__ A, const u8* __restrict__ BT,
                          const float* __restrict__ bias, u8* __restrict__ out) {
    __shared__ __align__(16) u8 As[16384];
    __shared__ __align__(16) u8 Bs[16384];
    const int lda = HID, ldb = HID, ldo = PFUSE;
    const int m0 = blockIdx.x * 128, n0 = blockIdx.y * 128;
    const int tid  = threadIdx.x;
    const int lane = tid & 63;
    const int wave = tid >> 6;          // 0..7
    const int wm = wave >> 2, wn = wave & 3;
    const int q = lane >> 4, lrow = lane & 15;
    const int sw = lrow & 7;

    int aofs[2], bofs[2], lbase[2];
    #pragma unroll
    for (int p = 0; p < 2; p++) {
        int pg = wave * 128 + p * 64 + lane;
        int row = pg >> 3, gcol = (pg & 7) ^ (row & 7);
        aofs[p]  = row * lda + gcol * 16;
        bofs[p]  = row * ldb + gcol * 16;
        lbase[p] = (wave * 128 + p * 64) * 16;
    }

    f32x4 acc[4][2];
    #pragma unroll
    for (int mt = 0; mt < 4; mt++)
        #pragma unroll
        for (int nt = 0; nt < 2; nt++)
            acc[mt][nt] = (f32x4)(0.0f);

    const u8* Ab = A  + (size_t)m0 * lda;
    const u8* Bb = BT + (size_t)n0 * ldb;

    const int aLo = ((wm * 64 + lrow) * 8 + ((2 * q)     ^ sw)) * 16;
    const int aHi = ((wm * 64 + lrow) * 8 + ((2 * q + 1) ^ sw)) * 16;
    const int bLo = ((wn * 32 + lrow) * 8 + ((2 * q)     ^ sw)) * 16;
    const int bHi = ((wn * 32 + lrow) * 8 + ((2 * q + 1) ^ sw)) * 16;

    for (int k0 = 0; k0 < HID; k0 += 128) {
        #pragma unroll
        for (int p = 0; p < 2; p++) {
            load16(Ab + k0 + aofs[p], As + lbase[p]);
            load16(Bb + k0 + bofs[p], Bs + lbase[p]);
        }
        __syncthreads();
        Frag fb[2];
        #pragma unroll
        for (int t = 0; t < 2; t++) {
            fb[t].half.lo = *reinterpret_cast<const i32x4*>(Bs + bLo + t * 2048);
            fb[t].half.hi = *reinterpret_cast<const i32x4*>(Bs + bHi + t * 2048);
        }
        #pragma unroll
        for (int mt = 0; mt < 4; mt++) {
            Frag fa;
            fa.half.lo = *reinterpret_cast<const i32x4*>(As + aLo + mt * 2048);
            fa.half.hi = *reinterpret_cast<const i32x4*>(As + aHi + mt * 2048);
            #pragma unroll
            for (int nt = 0; nt < 2; nt++)
                acc[mt][nt] = __builtin_amdgcn_mfma_scale_f32_16x16x128_f8f6f4(
                    fa.v, fb[nt].v, acc[mt][nt],
                    0, 0, 0, 0x7F7F7F7F, 0, 0x7A7A7A7A);
        }
        __syncthreads();
    }

    int colg[2]; float bias_v[2];
    #pragma unroll
    for (int nt = 0; nt < 2; nt++) {
        colg[nt] = n0 + wn * 32 + nt * 16 + lrow;
        bias_v[nt] = (colg[nt] < PREAL) ? bias[colg[nt]] : 0.0f;
    }
    #pragma unroll
    for (int mt = 0; mt < 4; mt++) {
        int rowb = m0 + wm * 64 + mt * 16 + q * 4;
        #pragma unroll
        for (int r = 0; r < 4; r++) {
            int tok = rowb + r;
            #pragma unroll
            for (int nt = 0; nt < 2; nt++)
                out[(size_t)tok * ldo + colg[nt]] = to_e4m3(acc[mt][nt][r] + bias_v[nt]);
        }
    }
}

// =====================================================================
// prep: all casts/transposes/init fused into one dispatch (branch by range)
// =====================================================================
__device__ __forceinline__ void do_transpose(const float* __restrict__ W, u8* __restrict__ WT,
                                             int K, int N, int Kpad, float scale,
                                             int bx, int by, float (*tile)[65]) {
    int n0 = bx * 64, k0 = by * 64;
    int c2 = threadIdx.x & 31;           // column pair 0..31
    int rg = threadIdx.x >> 5;           // row group 0..7
    int n = n0 + c2 * 2;
    #pragma unroll
    for (int j = 0; j < 8; j++) {
        int k = k0 + rg + j * 8;
        float2 v;
        if (k < K && n + 1 < N) {
            v = *reinterpret_cast<const float2*>(&W[(size_t)k * N + n]);
        } else {
            v.x = (k < K && n     < N) ? W[(size_t)k * N + n]     : 0.0f;
            v.y = (k < K && n + 1 < N) ? W[(size_t)k * N + n + 1] : 0.0f;
        }
        tile[rg + j * 8][c2 * 2]     = v.x * scale;
        tile[rg + j * 8][c2 * 2 + 1] = v.y * scale;
    }
    __syncthreads();
    int nn = threadIdx.x >> 2, kb = (threadIdx.x & 3) * 16;   // nn 0..63, kb 0/16/32/48
    union { u8 b[16]; uint4 u; } v;
    #pragma unroll
    for (int j = 0; j < 16; j++) v.b[j] = to_e4m3(tile[kb + j][nn]);
    *reinterpret_cast<uint4*>(WT + (size_t)(n0 + nn) * Kpad + k0 + kb) = v.u;
}

#define NBT_HEAD 4096   // 256 x 16 (covers 16384 padded cols, zero-filled)
#define NBT_CAST 1024
#define NBT_T0W   768   // 192 x 4 (covers 12288 padded cols)
#define NBT_T1W   256   // 128 x 2
#define NBT_T0P    64   // 4 x 16
#define NBT_T1P    32   // 2 x 16
#define NBT_INIT   16

__global__ void prep_kernel(const float* __restrict__ inp, const int* __restrict__ labels,
                            const float* __restrict__ head_W,
                            const float* __restrict__ t0_pW, const float* __restrict__ t0_pb,
                            const float* __restrict__ t0_W,
                            const float* __restrict__ t1_pW, const float* __restrict__ t1_pb,
                            const float* __restrict__ t1_W,
                            u8* __restrict__ inp_f8, u8* __restrict__ headW8,
                            u8* __restrict__ fpW8, u8* __restrict__ t0W8, u8* __restrict__ t1W8,
                            float* __restrict__ acc6, int* __restrict__ tgts,
                            float* __restrict__ pbias, float* __restrict__ out) {
    __shared__ float tile[64][65];
    int b = blockIdx.x;
    if (b < NBT_HEAD) {
        do_transpose(head_W, headW8, HID, NHEAD, HID, 32.0f, b % 256, b / 256, tile);
    } else if (b < NBT_HEAD + NBT_CAST) {
        int r = b - NBT_HEAD;
        int i = r * 256 + threadIdx.x;          // i < 262144 = M_TOK*HID/4
        float4 v = reinterpret_cast<const float4*>(inp)[i];
        uchar4 o8;
        o8.x = to_e4m3(v.x); o8.y = to_e4m3(v.y); o8.z = to_e4m3(v.z); o8.w = to_e4m3(v.w);
        reinterpret_cast<uchar4*>(inp_f8)[i] = o8;
    } else if (b < NBT_HEAD + NBT_CAST + NBT_T0W) {
        int r = b - (NBT_HEAD + NBT_CAST);
        do_transpose(t0_W, t0W8, P0, N0, P0, 32.0f, r % 192, r / 192, tile);
    } else if (b < NBT_HEAD + NBT_CAST + NBT_T0W + NBT_T1W) {
        int r = b - (NBT_HEAD + NBT_CAST + NBT_T0W);
        do_transpose(t1_W, t1W8, P1, N1, 128, 32.0f, r % 128, r / 128, tile);
    } else if (b < NBT_HEAD + NBT_CAST + NBT_T0W + NBT_T1W + NBT_T0P) {
        int r = b - (NBT_HEAD + NBT_CAST + NBT_T0W + NBT_T1W);
        do_transpose(t0_pW, fpW8, HID, P0, HID, 32.0f, r % 4, r / 4, tile);
    } else if (b < NBT_HEAD + NBT_CAST + NBT_T0W + NBT_T1W + NBT_T0P + NBT_T1P) {
        int r = b - (NBT_HEAD + NBT_CAST + NBT_T0W + NBT_T1W + NBT_T0P);
        do_transpose(t1_pW, fpW8 + 256 * HID, HID, P1, HID, 32.0f, r % 2, r / 2, tile);
    } else {
        int r = b - (NBT_HEAD + NBT_CAST + NBT_T0W + NBT_T1W + NBT_T0P + NBT_T1P);
        int t = r * 256 + threadIdx.x;          // t < 4096
        for (int j = t; j < 6 * M_TOK; j += M_TOK) acc6[j] = 0.0f;
        if (t == 0) out[0] = 0.0f;
        if (t < PFUSE) pbias[t] = (t < 256) ? t0_pb[t] : ((t < PREAL) ? t1_pb[t - 256] : 0.0f);
        int lbl = labels[t];
        tgts[t]             = (lbl < 16000) ? lbl : ((lbl < 28000) ? 16000 : 16001);
        int t0 = lbl - 16000; t0 = t0 < 0 ? 0 : (t0 > 11999 ? 11999 : t0);
        int t1 = lbl - 28000; t1 = t1 < 0 ? 0 : (t1 > 7999  ? 7999  : t1);
        tgts[M_TOK + t]     = t0;
        tgts[2 * M_TOK + t] = t1;
    }
}

// ---------------- finalize: per-token loss, mask, mean ----------------
__global__ void finalize_kernel(const int* __restrict__ labels, const float* __restrict__ acc6,
                                float* __restrict__ out) {
    int t = blockIdx.x * blockDim.x + threadIdx.x;   // 4096 threads
    const float* sumH = acc6;
    const float* labH = acc6 + M_TOK;
    const float* sum0 = acc6 + 2 * M_TOK;
    const float* lab0 = acc6 + 3 * M_TOK;
    const float* sum1 = acc6 + 4 * M_TOK;
    const float* lab1 = acc6 + 5 * M_TOK;
    int lbl = labels[t];
    float l = 0.0f;
    if (lbl != 0) {
        l = logf(sumH[t]) - labH[t];
        if (lbl >= 16000 && lbl < 28000) l += logf(sum0[t]) - lab0[t];
        else if (lbl >= 28000)           l += logf(sum1[t]) - lab1[t];
    }
    l *= (1.0f / (float)M_TOK);
    #pragma unroll
    for (int off = 1; off < 64; off <<= 1) l += __shfl_xor(l, off);
    __shared__ float red[4];
    if ((threadIdx.x & 63) == 0) red[threadIdx.x >> 6] = l;
    __syncthreads();
    if (threadIdx.x == 0) atomicAdd(out, red[0] + red[1] + red[2] + red[3]);
}

// ---------------- host launcher ----------------
extern "C" void kernel_launch(void* const* d_in, const int* in_sizes, int n_in,
                              void* d_out, int out_size, void* d_ws, size_t ws_size,
                              hipStream_t stream) {
    const float* inp    = (const float*)d_in[0];
    const int*   labels = (const int*)  d_in[1];
    const float* head_W = (const float*)d_in[2];
    const float* head_b = (const float*)d_in[3];
    const float* t0_pW  = (const float*)d_in[4];
    const float* t0_pb  = (const float*)d_in[5];
    const float* t0_W   = (const float*)d_in[6];
    const float* t0_b   = (const float*)d_in[7];
    const float* t1_pW  = (const float*)d_in[8];
    const float* t1_pb  = (const float*)d_in[9];
    const float* t1_W   = (const float*)d_in[10];
    const float* t1_b   = (const float*)d_in[11];
    float* out = (float*)d_out;

    char* ws = (char*)d_ws;
    size_t off = 0;
    auto alloc = [&](size_t bytes) { char* p = ws + off; off += (bytes + 255) & ~(size_t)255; return p; };
    u8*    inp_f8  = (u8*)   alloc((size_t)M_TOK * HID);
    u8*    headW8  = (u8*)   alloc((size_t)NHEAD_PAD * HID);
    u8*    fpW8    = (u8*)   alloc((size_t)PFUSE * HID);
    u8*    t0W8    = (u8*)   alloc((size_t)N0_PAD * P0);
    u8*    t1W8    = (u8*)   alloc((size_t)N1_PAD * 128);
    u8*    proj8   = (u8*)   alloc((size_t)M_TOK * PFUSE);
    float* acc6    = (float*)alloc(6 * M_TOK * 4);
    int*   tgts    = (int*)  alloc(3 * M_TOK * 4);
    float* pbias   = (float*)alloc(PFUSE * 4);

    // stage 1: all conversions / transposes / init in one dispatch
    int nb = NBT_HEAD + NBT_CAST + NBT_T0W + NBT_T1W + NBT_T0P + NBT_T1P + NBT_INIT;
    prep_kernel<<<nb, 256, 0, stream>>>(inp, labels, head_W, t0_pW, t0_pb, t0_W,
                                        t1_pW, t1_pb, t1_W,
                                        inp_f8, headW8, fpW8, t0W8, t1W8,
                                        acc6, tgts, pbias, out);

    // stage 2: fused tail projections -> fp8 [M_TOK x 384]
    gemm_proj<<<dim3(M_TOK / 128, PFUSE / 128), 512, 0, stream>>>(inp_f8, fpW8, pbias, proj8);

    // stage 3: all three LSE GEMMs in one dispatch (head first = longest)
    Seg s0{inp_f8,      HID,   headW8, HID, head_b, HID, NHEAD, tgts,             acc6,             acc6 + M_TOK,     16 * (NHEAD_PAD / 256)};
    Seg s1{proj8,       PFUSE, t0W8,   P0,  t0_b,   P0,  N0,    tgts + M_TOK,     acc6 + 2 * M_TOK, acc6 + 3 * M_TOK, 16 * (N0_PAD / 256)};
    Seg s2{proj8 + 256, PFUSE, t1W8,   128, t1_b,   128, N1,    tgts + 2 * M_TOK, acc6 + 4 * M_TOK, acc6 + 5 * M_TOK, 16 * (N1_PAD / 256)};
    gemm_lse3<<<s0.nblk + s1.nblk + s2.nblk, 1024, 0, stream>>>(s0, s1, s2);

    // stage 4: reduce to scalar mean
    finalize_kernel<<<M_TOK / 256, 256, 0, stream>>>(labels, acc6, out);
}

// Round 9
// 301.463 us; speedup vs baseline: 1.1976x; 1.1976x over previous
//
#include <hip/hip_runtime.h>
#include <hip/hip_bf16.h>
#include <hip/hip_fp8.h>
#include <cstdint>
#include <cstddef>

// ---------------- problem constants ----------------
#define M_TOK 4096          // B*S = 4*1024 tokens
#define HID   1024
#define NHEAD 16002
#define NHEAD_PAD 16128     // 126*128
#define P0    256
#define N0    12000
#define N0_PAD 12032        // 94*128
#define P1    64
#define N1    8000
#define N1_PAD 8192         // 64*128
#define PFUSE 384           // fused proj width: 256 + 128(pad of 64)
#define PREAL 320           // real cols in fused proj: 256 + 64

typedef unsigned char u8;
typedef float f32x4 __attribute__((ext_vector_type(4)));
typedef int   i32x4 __attribute__((ext_vector_type(4)));
typedef int   i32x8 __attribute__((ext_vector_type(8)));

// async global->LDS, 16B per lane; lds ptr = wave-uniform base, HW scatters lane*16.
__device__ __forceinline__ void load16(const void* g, void* l) {
    __builtin_amdgcn_global_load_lds(
        (__attribute__((address_space(1))) void*)g,
        (__attribute__((address_space(3))) void*)l,
        16, 0, 0);
}

__device__ __forceinline__ u8 to_e4m3(float f) {
    __hip_fp8_e4m3 h(f);
    return (u8)h.__x;
}

union Frag { struct { i32x4 lo, hi; } half; i32x8 v; };

// =====================================================================
// Round-9 (= round-8 resubmit; infra failure, kernel never ran).
// lse3: BM=256 x BN=128 tile, BK=128, 8 waves (4x2) of the PROVEN 64x64
// wave tile (acc 64 AGPR + ~64 VGPR, fb[4]+fa ping-pong, verbatim
// round-6 wave work). Single-buffered 48 KB LDS (A 32K, B 16K),
// 2-barrier __syncthreads loop -> __launch_bounds__(512,4) = 2 BLOCKS/CU.
//
// WHY (ledger L1-L6): R6 (256^2, 1 block) won on staged-byte efficiency
// but lost cross-block overlap; R7 proved intra-block phasing is killed
// by barrier cost (~550cyc x 16 waves; +6 barriers == entire +55us).
// This config keeps near-R6 byte efficiency (967 MB vs 655; R5 was
// 1290 MB) AND restores the m114 two-barrier-domain overlap: one
// block's stage-drain+barrier hides under the other's LDS/MFMA phase.
// Barrier skew also halves at 8 waves/block.
//
// LDS layout per matrix: rows x 8 granules(16B), phys granule in row =
// g ^ (row&7) (HW-verified); staging pre-swizzles the GLOBAL address,
// LDS write stays linear (global_load_lds requirement).
// =====================================================================
struct Seg {
    const u8* A; int lda;
    const u8* BT; int ldb;
    const float* bias; int K; int realN;
    const int* tgt; float* sumexp; float* lab;
    int nblk;   // 16 m-tiles x NT n-tiles(128), NT even; nblk % 32 == 0
};

__launch_bounds__(512, 4)
__global__ void gemm_lse3(Seg s0, Seg s1, Seg s2) {
    __shared__ __align__(16) u8 As[32768];   // 256 x 128
    __shared__ __align__(16) u8 Bs[16384];   // 128 x 128

    int b = blockIdx.x;
    Seg sg; int rel;
    if (b < s0.nblk)                { sg = s0; rel = b; }
    else if (b < s0.nblk + s1.nblk) { sg = s1; rel = b - s0.nblk; }
    else                            { sg = s2; rel = b - s0.nblk - s1.nblk; }
    // L2-locality swizzle: 32-block groups = 16 m-tiles x 2 n-tiles.
    int pair = rel >> 5, inner = rel & 31;
    int m0 = (inner >> 1) * 256;
    int n0 = (pair * 2 + (inner & 1)) * 128;

    const int lda = sg.lda, ldb = sg.ldb;
    const int tid  = threadIdx.x;
    const int lane = tid & 63;
    const int wave = tid >> 6;          // 0..7
    const int wm = wave >> 1, wn = wave & 1;
    const int q = lane >> 4, lrow = lane & 15;
    const int sw = lrow & 7;

    // A staging: 2048 granules (256 rows x 8), 4 loads/thread.
    // B staging: 1024 granules (128 rows x 8), 2 loads/thread.
    int aofs[4], abase[4], bofs[2], bbase[2];
    #pragma unroll
    for (int p = 0; p < 4; p++) {
        int pg = wave * 256 + p * 64 + lane;          // 0..2047
        int row = pg >> 3, gcol = (pg & 7) ^ (row & 7);
        aofs[p]  = row * lda + gcol * 16;
        abase[p] = (wave * 256 + p * 64) * 16;
    }
    #pragma unroll
    for (int p = 0; p < 2; p++) {
        int pg = wave * 128 + p * 64 + lane;          // 0..1023
        int row = pg >> 3, gcol = (pg & 7) ^ (row & 7);
        bofs[p]  = row * ldb + gcol * 16;
        bbase[p] = (wave * 128 + p * 64) * 16;
    }

    f32x4 acc[4][4];
    #pragma unroll
    for (int mt = 0; mt < 4; mt++)
        #pragma unroll
        for (int nt = 0; nt < 4; nt++)
            acc[mt][nt] = (f32x4)(0.0f);

    const u8* Ab = sg.A  + (size_t)m0 * lda;
    const u8* Bb = sg.BT + (size_t)n0 * ldb;

    // fragment LDS byte offsets; +t*2048 per 16-row subtile.
    const int aLo = ((wm * 64 + lrow) * 8 + ((2 * q)     ^ sw)) * 16;
    const int aHi = ((wm * 64 + lrow) * 8 + ((2 * q + 1) ^ sw)) * 16;
    const int bLo = ((wn * 64 + lrow) * 8 + ((2 * q)     ^ sw)) * 16;
    const int bHi = ((wn * 64 + lrow) * 8 + ((2 * q + 1) ^ sw)) * 16;

    for (int k0 = 0; k0 < sg.K; k0 += 128) {
        #pragma unroll
        for (int p = 0; p < 4; p++)
            load16(Ab + k0 + aofs[p], As + abase[p]);
        #pragma unroll
        for (int p = 0; p < 2; p++)
            load16(Bb + k0 + bofs[p], Bs + bbase[p]);
        __syncthreads();   // includes vmcnt(0) drain; 2nd block/CU covers it

        Frag fb[4];
        #pragma unroll
        for (int t = 0; t < 4; t++) {
            fb[t].half.lo = *reinterpret_cast<const i32x4*>(Bs + bLo + t * 2048);
            fb[t].half.hi = *reinterpret_cast<const i32x4*>(Bs + bHi + t * 2048);
        }
        Frag fa[2];
        fa[0].half.lo = *reinterpret_cast<const i32x4*>(As + aLo);
        fa[0].half.hi = *reinterpret_cast<const i32x4*>(As + aHi);
        #pragma unroll
        for (int mt = 0; mt < 4; mt++) {
            if (mt < 3) {
                fa[(mt + 1) & 1].half.lo = *reinterpret_cast<const i32x4*>(As + aLo + (mt + 1) * 2048);
                fa[(mt + 1) & 1].half.hi = *reinterpret_cast<const i32x4*>(As + aHi + (mt + 1) * 2048);
            }
            #pragma unroll
            for (int nt = 0; nt < 4; nt++)
                acc[mt][nt] = __builtin_amdgcn_mfma_scale_f32_16x16x128_f8f6f4(
                    fa[mt & 1].v, fb[nt].v, acc[mt][nt],
                    0, 0,                      // cbsz/blgp = fp8 e4m3
                    0, 0x7F7F7F7F,             // A scale: 2^0
                    0, 0x7A7A7A7A);            // B scale: 2^-5
        }
        __syncthreads();   // reads retired before next overwrite
    }

    // ---- epilogue: C/D (16x16): col = lane&15, row = (lane>>4)*4 + reg
    int colg[4]; float bias_v[4];
    #pragma unroll
    for (int nt = 0; nt < 4; nt++) {
        colg[nt] = n0 + wn * 64 + nt * 16 + lrow;
        bias_v[nt] = (colg[nt] < sg.realN) ? sg.bias[colg[nt]] : 0.0f;
    }

    float* sred = reinterpret_cast<float*>(As);   // [2][256], reuse A LDS

    #pragma unroll
    for (int mt = 0; mt < 4; mt++) {
        int rloc = wm * 64 + mt * 16 + q * 4;     // token row within tile (0..255)
        #pragma unroll
        for (int r = 0; r < 4; r++) {
            int tok = m0 + rloc + r;
            int tg = sg.tgt[tok];
            float ps = 0.0f;
            #pragma unroll
            for (int nt = 0; nt < 4; nt++) {
                if (colg[nt] < sg.realN) {
                    float logit = acc[mt][nt][r] + bias_v[nt];
                    ps += __expf(logit);
                    if (colg[nt] == tg) atomicAdd(&sg.lab[tok], logit);
                }
            }
            ps += __shfl_xor(ps, 1);
            ps += __shfl_xor(ps, 2);
            ps += __shfl_xor(ps, 4);
            ps += __shfl_xor(ps, 8);
            // slice write: (wn, row) written by exactly one lane
            if (lrow == 0) sred[wn * 256 + rloc + r] = ps;
        }
    }
    __syncthreads();
    if (tid < 256) {
        float v = sred[tid] + sred[256 + tid];
        atomicAdd(&sg.sumexp[m0 + tid], v);
    }
}

// =====================================================================
// proj GEMM body (round-6 proven 128x128, 8 waves of 64x32) as a device
// function so it can run as blocks of the fused prep2 dispatch.
// =====================================================================
__device__ __forceinline__ void proj_body(const u8* __restrict__ A, const u8* __restrict__ BT,
                                          const float* __restrict__ bias, u8* __restrict__ out,
                                          int m0, int n0, u8* As, u8* Bs) {
    const int lda = HID, ldb = HID, ldo = PFUSE;
    const int tid  = threadIdx.x;
    const int lane = tid & 63;
    const int wave = tid >> 6;          // 0..7
    const int wm = wave >> 2, wn = wave & 3;
    const int q = lane >> 4, lrow = lane & 15;
    const int sw = lrow & 7;

    int aofs[2], bofs[2], lbase[2];
    #pragma unroll
    for (int p = 0; p < 2; p++) {
        int pg = wave * 128 + p * 64 + lane;
        int row = pg >> 3, gcol = (pg & 7) ^ (row & 7);
        aofs[p]  = row * lda + gcol * 16;
        bofs[p]  = row * ldb + gcol * 16;
        lbase[p] = (wave * 128 + p * 64) * 16;
    }

    f32x4 acc[4][2];
    #pragma unroll
    for (int mt = 0; mt < 4; mt++)
        #pragma unroll
        for (int nt = 0; nt < 2; nt++)
            acc[mt][nt] = (f32x4)(0.0f);

    const u8* Ab = A  + (size_t)m0 * lda;
    const u8* Bb = BT + (size_t)n0 * ldb;

    const int aLo = ((wm * 64 + lrow) * 8 + ((2 * q)     ^ sw)) * 16;
    const int aHi = ((wm * 64 + lrow) * 8 + ((2 * q + 1) ^ sw)) * 16;
    const int bLo = ((wn * 32 + lrow) * 8 + ((2 * q)     ^ sw)) * 16;
    const int bHi = ((wn * 32 + lrow) * 8 + ((2 * q + 1) ^ sw)) * 16;

    for (int k0 = 0; k0 < HID; k0 += 128) {
        #pragma unroll
        for (int p = 0; p < 2; p++) {
            load16(Ab + k0 + aofs[p], As + lbase[p]);
            load16(Bb + k0 + bofs[p], Bs + lbase[p]);
        }
        __syncthreads();
        Frag fb[2];
        #pragma unroll
        for (int t = 0; t < 2; t++) {
            fb[t].half.lo = *reinterpret_cast<const i32x4*>(Bs + bLo + t * 2048);
            fb[t].half.hi = *reinterpret_cast<const i32x4*>(Bs + bHi + t * 2048);
        }
        #pragma unroll
        for (int mt = 0; mt < 4; mt++) {
            Frag fa;
            fa.half.lo = *reinterpret_cast<const i32x4*>(As + aLo + mt * 2048);
            fa.half.hi = *reinterpret_cast<const i32x4*>(As + aHi + mt * 2048);
            #pragma unroll
            for (int nt = 0; nt < 2; nt++)
                acc[mt][nt] = __builtin_amdgcn_mfma_scale_f32_16x16x128_f8f6f4(
                    fa.v, fb[nt].v, acc[mt][nt],
                    0, 0, 0, 0x7F7F7F7F, 0, 0x7A7A7A7A);
        }
        __syncthreads();
    }

    int colg[2]; float bias_v[2];
    #pragma unroll
    for (int nt = 0; nt < 2; nt++) {
        colg[nt] = n0 + wn * 32 + nt * 16 + lrow;
        bias_v[nt] = (colg[nt] < PREAL) ? bias[colg[nt]] : 0.0f;
    }
    #pragma unroll
    for (int mt = 0; mt < 4; mt++) {
        int rowb = m0 + wm * 64 + mt * 16 + q * 4;
        #pragma unroll
        for (int r = 0; r < 4; r++) {
            int tok = rowb + r;
            #pragma unroll
            for (int nt = 0; nt < 2; nt++)
                out[(size_t)tok * ldo + colg[nt]] = to_e4m3(acc[mt][nt][r] + bias_v[nt]);
        }
    }
}

// =====================================================================
// 512-thread 64x64 transpose tile: float2 row reads, fp8 8B stores.
// =====================================================================
__device__ __forceinline__ void do_transpose512(const float* __restrict__ W, u8* __restrict__ WT,
                                                int K, int N, int Kpad, float scale,
                                                int bx, int by, float (*tile)[65]) {
    int n0 = bx * 64, k0 = by * 64;
    int c2 = threadIdx.x & 31;           // column pair 0..31
    int rg = threadIdx.x >> 5;           // row group 0..15
    int n = n0 + c2 * 2;
    #pragma unroll
    for (int j = 0; j < 4; j++) {
        int k = k0 + rg + j * 16;
        float2 v;
        if (k < K && n + 1 < N) {
            v = *reinterpret_cast<const float2*>(&W[(size_t)k * N + n]);
        } else {
            v.x = (k < K && n     < N) ? W[(size_t)k * N + n]     : 0.0f;
            v.y = (k < K && n + 1 < N) ? W[(size_t)k * N + n + 1] : 0.0f;
        }
        tile[rg + j * 16][c2 * 2]     = v.x * scale;
        tile[rg + j * 16][c2 * 2 + 1] = v.y * scale;
    }
    __syncthreads();
    int nn = threadIdx.x >> 3, kb = (threadIdx.x & 7) * 8;   // nn 0..63, kb 0..56
    union { u8 b[8]; uint2 u; } v;
    #pragma unroll
    for (int j = 0; j < 8; j++) v.b[j] = to_e4m3(tile[kb + j][nn]);
    *reinterpret_cast<uint2*>(WT + (size_t)(n0 + nn) * Kpad + k0 + kb) = v.u;
}

// =====================================================================
// prep1: inp cast + proj-weight transposes + init (everything proj needs)
// 512 threads/block.
// =====================================================================
#define P1_CAST 512    // 512 x 512 float4 = 262144
#define P1_T0P   64    // 4 x 16
#define P1_T1P   32    // 2 x 16 (2nd bx zero-fills PFUSE pad rows 320..383)
#define P1_INIT   8    // 8 x 512 = 4096

__global__ void prep1_kernel(const float* __restrict__ inp, const int* __restrict__ labels,
                             const float* __restrict__ t0_pW, const float* __restrict__ t0_pb,
                             const float* __restrict__ t1_pW, const float* __restrict__ t1_pb,
                             u8* __restrict__ inp_f8, u8* __restrict__ fpW8,
                             float* __restrict__ acc6, int* __restrict__ tgts,
                             float* __restrict__ pbias, float* __restrict__ out) {
    __shared__ float tile[64][65];
    int b = blockIdx.x;
    if (b < P1_CAST) {
        int i = b * 512 + threadIdx.x;          // < 262144 = M_TOK*HID/4
        float4 v = reinterpret_cast<const float4*>(inp)[i];
        uchar4 o8;
        o8.x = to_e4m3(v.x); o8.y = to_e4m3(v.y); o8.z = to_e4m3(v.z); o8.w = to_e4m3(v.w);
        reinterpret_cast<uchar4*>(inp_f8)[i] = o8;
    } else if (b < P1_CAST + P1_T0P) {
        int r = b - P1_CAST;
        do_transpose512(t0_pW, fpW8, HID, P0, HID, 32.0f, r % 4, r / 4, tile);
    } else if (b < P1_CAST + P1_T0P + P1_T1P) {
        int r = b - (P1_CAST + P1_T0P);
        do_transpose512(t1_pW, fpW8 + 256 * HID, HID, P1, HID, 32.0f, r % 2, r / 2, tile);
    } else {
        int r = b - (P1_CAST + P1_T0P + P1_T1P);
        int t = r * 512 + threadIdx.x;          // t < 4096
        for (int j = t; j < 6 * M_TOK; j += M_TOK) acc6[j] = 0.0f;
        if (t == 0) out[0] = 0.0f;
        if (t < PFUSE) pbias[t] = (t < 256) ? t0_pb[t] : ((t < PREAL) ? t1_pb[t - 256] : 0.0f);
        int lbl = labels[t];
        tgts[t]             = (lbl < 16000) ? lbl : ((lbl < 28000) ? 16000 : 16001);
        int t0 = lbl - 16000; t0 = t0 < 0 ? 0 : (t0 > 11999 ? 11999 : t0);
        int t1 = lbl - 28000; t1 = t1 < 0 ? 0 : (t1 > 7999  ? 7999  : t1);
        tgts[M_TOK + t]     = t0;
        tgts[2 * M_TOK + t] = t1;
    }
}

// =====================================================================
// prep2: big weight transposes (head/t0_W/t1_W) FUSED with the proj GEMM
// blocks (independent: proj reads only prep1 outputs). proj's ~10-15us
// serial time hides under the 5040 transpose blocks.
// =====================================================================
#define P2_HEAD 4032   // 252 x 16
#define P2_T0W   752   // 188 x 4
#define P2_T1W   256   // 128 x 2
#define P2_PROJ   96   // 32 m x 3 n

__launch_bounds__(512, 4)
__global__ void prep2_kernel(const float* __restrict__ head_W,
                             const float* __restrict__ t0_W, const float* __restrict__ t1_W,
                             const u8* __restrict__ inp_f8, const u8* __restrict__ fpW8,
                             const float* __restrict__ pbias,
                             u8* __restrict__ headW8, u8* __restrict__ t0W8,
                             u8* __restrict__ t1W8, u8* __restrict__ proj8) {
    __shared__ __align__(16) u8 smem[32768];
    int b = blockIdx.x;
    if (b < P2_HEAD) {
        do_transpose512(head_W, headW8, HID, NHEAD, HID, 32.0f, b % 252, b / 252,
                        reinterpret_cast<float (*)[65]>(smem));
    } else if (b < P2_HEAD + P2_T0W) {
        int r = b - P2_HEAD;
        do_transpose512(t0_W, t0W8, P0, N0, P0, 32.0f, r % 188, r / 188,
                        reinterpret_cast<float (*)[65]>(smem));
    } else if (b < P2_HEAD + P2_T0W + P2_T1W) {
        int r = b - (P2_HEAD + P2_T0W);
        do_transpose512(t1_W, t1W8, P1, N1, 128, 32.0f, r % 128, r / 128,
                        reinterpret_cast<float (*)[65]>(smem));
    } else {
        int r = b - (P2_HEAD + P2_T0W + P2_T1W);
        int m0 = (r & 31) * 128;
        int n0 = (r >> 5) * 128;
        proj_body(inp_f8, fpW8, pbias, proj8, m0, n0, smem, smem + 16384);
    }
}

// ---------------- finalize: per-token loss, mask, mean ----------------
__global__ void finalize_kernel(const int* __restrict__ labels, const float* __restrict__ acc6,
                                float* __restrict__ out) {
    int t = blockIdx.x * blockDim.x + threadIdx.x;   // 4096 threads
    const float* sumH = acc6;
    const float* labH = acc6 + M_TOK;
    const float* sum0 = acc6 + 2 * M_TOK;
    const float* lab0 = acc6 + 3 * M_TOK;
    const float* sum1 = acc6 + 4 * M_TOK;
    const float* lab1 = acc6 + 5 * M_TOK;
    int lbl = labels[t];
    float l = 0.0f;
    if (lbl != 0) {
        l = logf(sumH[t]) - labH[t];
        if (lbl >= 16000 && lbl < 28000) l += logf(sum0[t]) - lab0[t];
        else if (lbl >= 28000)           l += logf(sum1[t]) - lab1[t];
    }
    l *= (1.0f / (float)M_TOK);
    #pragma unroll
    for (int off = 1; off < 64; off <<= 1) l += __shfl_xor(l, off);
    __shared__ float red[4];
    if ((threadIdx.x & 63) == 0) red[threadIdx.x >> 6] = l;
    __syncthreads();
    if (threadIdx.x == 0) atomicAdd(out, red[0] + red[1] + red[2] + red[3]);
}

// ---------------- host launcher ----------------
extern "C" void kernel_launch(void* const* d_in, const int* in_sizes, int n_in,
                              void* d_out, int out_size, void* d_ws, size_t ws_size,
                              hipStream_t stream) {
    const float* inp    = (const float*)d_in[0];
    const int*   labels = (const int*)  d_in[1];
    const float* head_W = (const float*)d_in[2];
    const float* head_b = (const float*)d_in[3];
    const float* t0_pW  = (const float*)d_in[4];
    const float* t0_pb  = (const float*)d_in[5];
    const float* t0_W   = (const float*)d_in[6];
    const float* t0_b   = (const float*)d_in[7];
    const float* t1_pW  = (const float*)d_in[8];
    const float* t1_pb  = (const float*)d_in[9];
    const float* t1_W   = (const float*)d_in[10];
    const float* t1_b   = (const float*)d_in[11];
    float* out = (float*)d_out;

    char* ws = (char*)d_ws;
    size_t off = 0;
    auto alloc = [&](size_t bytes) { char* p = ws + off; off += (bytes + 255) & ~(size_t)255; return p; };
    u8*    inp_f8  = (u8*)   alloc((size_t)M_TOK * HID);
    u8*    headW8  = (u8*)   alloc((size_t)NHEAD_PAD * HID);
    u8*    fpW8    = (u8*)   alloc((size_t)PFUSE * HID);
    u8*    t0W8    = (u8*)   alloc((size_t)N0_PAD * P0);
    u8*    t1W8    = (u8*)   alloc((size_t)N1_PAD * 128);
    u8*    proj8   = (u8*)   alloc((size_t)M_TOK * PFUSE);
    float* acc6    = (float*)alloc(6 * M_TOK * 4);
    int*   tgts    = (int*)  alloc(3 * M_TOK * 4);
    float* pbias   = (float*)alloc(PFUSE * 4);

    // stage 1: everything the proj GEMM needs (inp cast, proj weights, init)
    prep1_kernel<<<P1_CAST + P1_T0P + P1_T1P + P1_INIT, 512, 0, stream>>>(
        inp, labels, t0_pW, t0_pb, t1_pW, t1_pb,
        inp_f8, fpW8, acc6, tgts, pbias, out);

    // stage 2: big transposes FUSED with proj GEMM (independent blocks)
    prep2_kernel<<<P2_HEAD + P2_T0W + P2_T1W + P2_PROJ, 512, 0, stream>>>(
        head_W, t0_W, t1_W, inp_f8, fpW8, pbias,
        headW8, t0W8, t1W8, proj8);

    // stage 3: all three LSE GEMMs in one dispatch (head first = longest)
    Seg s0{inp_f8,      HID,   headW8, HID, head_b, HID, NHEAD, tgts,             acc6,             acc6 + M_TOK,     16 * (NHEAD_PAD / 128)};
    Seg s1{proj8,       PFUSE, t0W8,   P0,  t0_b,   P0,  N0,    tgts + M_TOK,     acc6 + 2 * M_TOK, acc6 + 3 * M_TOK, 16 * (N0_PAD / 128)};
    Seg s2{proj8 + 256, PFUSE, t1W8,   128, t1_b,   128, N1,    tgts + 2 * M_TOK, acc6 + 4 * M_TOK, acc6 + 5 * M_TOK, 16 * (N1_PAD / 128)};
    gemm_lse3<<<s0.nblk + s1.nblk + s2.nblk, 512, 0, stream>>>(s0, s1, s2);

    // stage 4: reduce to scalar mean
    finalize_kernel<<<M_TOK / 256, 256, 0, stream>>>(labels, acc6, out);
}